// Round 1
// baseline (1142.644 us; speedup 1.0000x reference)
//
#include <hip/hip_runtime.h>

#define N_NODES 50000
#define N_EDGES 800000
#define HID 128
#define EPS 1e-5f

// ---------------- CSR build (once per launch; reused by both layers) ----------------
__global__ void hist_kernel(const int* __restrict__ ei, int* __restrict__ counts) {
  int e = blockIdx.x * blockDim.x + threadIdx.x;
  if (e < N_EDGES) atomicAdd(&counts[ei[N_EDGES + e]], 1);
}

// single block, 1024 threads: exclusive scan of counts -> offsets (and cursor copy)
__global__ void scan_kernel(const int* __restrict__ counts, int* __restrict__ offsets,
                            int* __restrict__ cursor) {
  __shared__ int wtot[16];
  __shared__ int carry_s;
  const int tid = threadIdx.x;
  const int lane = tid & 63, w = tid >> 6;
  if (tid == 0) carry_s = 0;
  __syncthreads();
  for (int base = 0; base < N_NODES; base += 1024) {
    int i = base + tid;
    int v = (i < N_NODES) ? counts[i] : 0;
    int s = v;
#pragma unroll
    for (int off = 1; off < 64; off <<= 1) {
      int t = __shfl_up(s, off);
      if (lane >= off) s += t;
    }
    if (lane == 63) wtot[w] = s;
    __syncthreads();                       // wtot visible
    int c0 = carry_s;
    int woff = 0;
    for (int j = 0; j < 16; ++j) { int t = wtot[j]; if (j < w) woff += t; }
    int excl = c0 + woff + (s - v);
    if (i < N_NODES) { offsets[i] = excl; cursor[i] = excl; }
    __syncthreads();                       // all c0/wtot reads done
    if (tid == 1023) carry_s = c0 + woff + s;  // chunk total appended
    __syncthreads();                       // carry visible before next iter
  }
  if (tid == 0) offsets[N_NODES] = carry_s;
}

__global__ void scatter_kernel(const int* __restrict__ ei, int* __restrict__ cursor,
                               int* __restrict__ csr_rows) {
  int e = blockIdx.x * blockDim.x + threadIdx.x;
  if (e < N_EDGES) {
    int c = ei[N_EDGES + e];
    int pos = atomicAdd(&cursor[c], 1);
    csr_rows[pos] = ei[e];
  }
}

// ---------------- node GEMM ----------------
// out[row][c] = sum_k A[row][k] * W[c*ldw + koff + k]  (+bias[c]) (+deg[row]*bias2[c]) (+=out if accum)
// tile 64 rows x 128 cols; K=128 in 2 chunks of 64; 256 threads; thread = 4 rows x 8 cols.
// LDS 50KB -> 3 blocks/CU. In-place (out==A) is safe: each block reads all its A rows
// (both k-chunks) before the epilogue writes, and blocks own disjoint rows.
__global__ __launch_bounds__(256, 3)
void gemm_kernel(const float* __restrict__ A, const float* __restrict__ W,
                 const float* __restrict__ bias, const int* __restrict__ deg,
                 const float* __restrict__ bias2, float* __restrict__ out,
                 int ldw, int koff, int accum) {
  __shared__ float Wt[64 * 132];  // [kk][c], stride 132: conflict-free b128 col reads
  __shared__ float As[64 * 68];   // [kk][row], stride 68: 2-way (free) b128 row reads
  const int tid = threadIdx.x;
  const int tr = tid & 15;   // rows tr*4 .. +3
  const int tc = tid >> 4;   // cols tc*8 .. +7
  const int r0 = blockIdx.x * 64;

  float acc[4][8];
#pragma unroll
  for (int i = 0; i < 4; ++i)
#pragma unroll
    for (int j = 0; j < 8; ++j) acc[i][j] = 0.f;

  for (int kc = 0; kc < 128; kc += 64) {
    __syncthreads();  // protect LDS from previous chunk's readers
    for (int u = tid; u < 64 * 128; u += 256) {  // W chunk, coalesced in k
      int kk = u & 63, c = u >> 6;
      Wt[kk * 132 + c] = W[(size_t)c * ldw + koff + kc + kk];
    }
    for (int u = tid; u < 64 * 64; u += 256) {   // A chunk, coalesced in k
      int kk = u & 63, row = u >> 6;
      int gr = r0 + row;
      As[kk * 68 + row] = (gr < N_NODES) ? A[(size_t)gr * HID + kc + kk] : 0.f;
    }
    __syncthreads();
#pragma unroll 4
    for (int kk = 0; kk < 64; ++kk) {
      float4 a4 = *(const float4*)&As[kk * 68 + tr * 4];
      float4 w0 = *(const float4*)&Wt[kk * 132 + tc * 8];
      float4 w1 = *(const float4*)&Wt[kk * 132 + tc * 8 + 4];
      float av[4] = {a4.x, a4.y, a4.z, a4.w};
      float wv[8] = {w0.x, w0.y, w0.z, w0.w, w1.x, w1.y, w1.z, w1.w};
#pragma unroll
      for (int i = 0; i < 4; ++i)
#pragma unroll
        for (int j = 0; j < 8; ++j) acc[i][j] = fmaf(av[i], wv[j], acc[i][j]);
    }
  }
#pragma unroll
  for (int i = 0; i < 4; ++i) {
    int row = r0 + tr * 4 + i;
    if (row >= N_NODES) continue;
    float* o = out + (size_t)row * HID + tc * 8;
    float dv = (deg != nullptr) ? (float)deg[row] : 0.f;
#pragma unroll
    for (int j = 0; j < 8; ++j) {
      float v = acc[i][j];
      if (bias) v += bias[tc * 8 + j];
      if (bias2) v += dv * bias2[tc * 8 + j];
      if (accum) v += o[j];
      o[j] = v;
    }
  }
}

// ---------------- edge aggregation: r[n] = sum_{e: col[e]=n} relu(p[row[e]] + q[n] + bm1) ----------------
__global__ void aggregate_kernel(const float* __restrict__ p, const float* __restrict__ q,
                                 const float* __restrict__ bm1,
                                 const int* __restrict__ offsets, const int* __restrict__ csr_rows,
                                 float* __restrict__ r) {
  int node = blockIdx.x * 2 + (threadIdx.x >> 7);
  if (node >= N_NODES) return;
  int c = threadIdx.x & 127;
  float qb = q[(size_t)node * HID + c] + bm1[c];
  float acc = 0.f;
  int i0 = offsets[node], i1 = offsets[node + 1];
  int idx = i0;
  for (; idx + 1 < i1; idx += 2) {
    int s0 = csr_rows[idx], s1 = csr_rows[idx + 1];
    float x0 = p[(size_t)s0 * HID + c] + qb;
    float x1 = p[(size_t)s1 * HID + c] + qb;
    acc += fmaxf(x0, 0.f) + fmaxf(x1, 0.f);
  }
  if (idx < i1) {
    int s0 = csr_rows[idx];
    acc += fmaxf(p[(size_t)s0 * HID + c] + qb, 0.f);
  }
  r[(size_t)node * HID + c] = acc;
}

// ---------------- residual + layernorm (in-place on h) ----------------
__global__ void ln_kernel(float* __restrict__ h, const float* __restrict__ upd,
                          const float* __restrict__ gamma, const float* __restrict__ beta) {
  int node = blockIdx.x * 4 + (threadIdx.x >> 6);
  int lane = threadIdx.x & 63;
  if (node >= N_NODES) return;
  size_t base = (size_t)node * HID;
  float v0 = h[base + lane] + upd[base + lane];
  float v1 = h[base + lane + 64] + upd[base + lane + 64];
  float s = v0 + v1, s2 = v0 * v0 + v1 * v1;
#pragma unroll
  for (int off = 32; off > 0; off >>= 1) {
    s += __shfl_xor(s, off);
    s2 += __shfl_xor(s2, off);
  }
  float mu = s * (1.f / 128.f);
  float var = s2 * (1.f / 128.f) - mu * mu;
  float inv = rsqrtf(var + EPS);
  h[base + lane] = (v0 - mu) * inv * gamma[lane] + beta[lane];
  h[base + lane + 64] = (v1 - mu) * inv * gamma[lane + 64] + beta[lane + 64];
}

extern "C" void kernel_launch(void* const* d_in, const int* in_sizes, int n_in,
                              void* d_out, int out_size, void* d_ws, size_t ws_size,
                              hipStream_t stream) {
  const float* x     = (const float*)d_in[0];
  const int*   ei    = (const int*)d_in[1];   // [2][E]: row=ei[e], col=ei[E+e]
  const float* W_enc = (const float*)d_in[2];
  const float* b_enc = (const float*)d_in[3];
  const float* Wm1   = (const float*)d_in[4]; // [2][128][256]
  const float* bm1   = (const float*)d_in[5];
  const float* Wm2   = (const float*)d_in[6]; // [2][128][128]
  const float* bm2   = (const float*)d_in[7];
  const float* Wu    = (const float*)d_in[8]; // [2][128][256]
  const float* bu    = (const float*)d_in[9];
  const float* gamma = (const float*)d_in[10];
  const float* beta  = (const float*)d_in[11];
  const float* W_out = (const float*)d_in[12];
  const float* b_out = (const float*)d_in[13];
  float* out = (float*)d_out;

  char* ws = (char*)d_ws;
  const size_t NB = (size_t)N_NODES * HID * sizeof(float);  // 25.6 MB
  float* h = (float*)(ws);
  float* p = (float*)(ws + NB);
  float* q = (float*)(ws + 2 * NB);
  int* counts  = (int*)(ws + 3 * NB);        // deg (kept intact)
  int* offsets = counts + N_NODES;           // N+1
  int* cursor  = offsets + N_NODES + 1;      // mutated by scatter
  int* csr     = cursor + N_NODES;           // [E] source rows grouped by col
  float* r = out;  // reuse d_out as agg scratch; final GEMM overwrites it

  hipMemsetAsync(counts, 0, N_NODES * sizeof(int), stream);
  hist_kernel<<<(N_EDGES + 255) / 256, 256, 0, stream>>>(ei, counts);
  scan_kernel<<<1, 1024, 0, stream>>>(counts, offsets, cursor);
  scatter_kernel<<<(N_EDGES + 255) / 256, 256, 0, stream>>>(ei, cursor, csr);

  const int GT = (N_NODES + 63) / 64;  // 782 row tiles

  // h = x @ W_enc.T + b_enc
  gemm_kernel<<<GT, 256, 0, stream>>>(x, W_enc, b_enc, nullptr, nullptr, h, HID, 0, 0);

  for (int l = 0; l < 2; ++l) {
    const float* Wm1l = Wm1 + (size_t)l * HID * 2 * HID;
    const float* Wm2l = Wm2 + (size_t)l * HID * HID;
    const float* Wul  = Wu  + (size_t)l * HID * 2 * HID;
    const float* bm1l = bm1 + l * HID;
    const float* bm2l = bm2 + l * HID;
    const float* bul  = bu  + l * HID;
    const float* gl   = gamma + l * HID;
    const float* bl   = beta + l * HID;

    // p = h @ Wm1[:, :128].T ; q = h @ Wm1[:, 128:].T   (bm1 added in aggregate)
    gemm_kernel<<<GT, 256, 0, stream>>>(h, Wm1l, nullptr, nullptr, nullptr, p, 2 * HID, 0, 0);
    gemm_kernel<<<GT, 256, 0, stream>>>(h, Wm1l, nullptr, nullptr, nullptr, q, 2 * HID, HID, 0);
    // r[n] = sum_{col[e]=n} relu(p[row[e]] + q[n] + bm1)
    aggregate_kernel<<<(N_NODES + 1) / 2, 256, 0, stream>>>(p, q, bm1l, offsets, csr, r);
    // agg = r @ Wm2.T + deg*bm2   (in-place on r)
    gemm_kernel<<<GT, 256, 0, stream>>>(r, Wm2l, nullptr, counts, bm2l, r, HID, 0, 0);
    // upd = h @ Wu[:, :128].T + bu ; upd += agg @ Wu[:, 128:].T
    gemm_kernel<<<GT, 256, 0, stream>>>(h, Wul, bul, nullptr, nullptr, p, 2 * HID, 0, 0);
    gemm_kernel<<<GT, 256, 0, stream>>>(r, Wul, nullptr, nullptr, nullptr, p, 2 * HID, HID, 1);
    // h = LN(h + upd) * gamma + beta
    ln_kernel<<<(N_NODES + 3) / 4, 256, 0, stream>>>(h, p, gl, bl);
  }

  // out = h @ W_out.T + b_out
  gemm_kernel<<<GT, 256, 0, stream>>>(h, W_out, b_out, nullptr, nullptr, out, HID, 0, 0);
}

// Round 2
// 1140.500 us; speedup vs baseline: 1.0019x; 1.0019x over previous
//
#include <hip/hip_runtime.h>

#define N_NODES 50000
#define N_EDGES 800000
#define HID 128
#define EPS 1e-5f

// ---------------- CSR build (once per launch; reused by both layers) ----------------
__global__ void hist_kernel(const int* __restrict__ ei, int* __restrict__ counts) {
  int e = blockIdx.x * blockDim.x + threadIdx.x;
  if (e < N_EDGES) atomicAdd(&counts[ei[N_EDGES + e]], 1);
}

// single block, 1024 threads: exclusive scan of counts -> offsets (and cursor copy)
__global__ void scan_kernel(const int* __restrict__ counts, int* __restrict__ offsets,
                            int* __restrict__ cursor) {
  __shared__ int wtot[16];
  __shared__ int carry_s;
  const int tid = threadIdx.x;
  const int lane = tid & 63, w = tid >> 6;
  if (tid == 0) carry_s = 0;
  __syncthreads();
  for (int base = 0; base < N_NODES; base += 1024) {
    int i = base + tid;
    int v = (i < N_NODES) ? counts[i] : 0;
    int s = v;
#pragma unroll
    for (int off = 1; off < 64; off <<= 1) {
      int t = __shfl_up(s, off);
      if (lane >= off) s += t;
    }
    if (lane == 63) wtot[w] = s;
    __syncthreads();                       // wtot visible
    int c0 = carry_s;
    int woff = 0;
    for (int j = 0; j < 16; ++j) { int t = wtot[j]; if (j < w) woff += t; }
    int excl = c0 + woff + (s - v);
    if (i < N_NODES) { offsets[i] = excl; cursor[i] = excl; }
    __syncthreads();                       // all c0/wtot reads done
    if (tid == 1023) carry_s = c0 + woff + s;  // chunk total appended
    __syncthreads();                       // carry visible before next iter
  }
  if (tid == 0) offsets[N_NODES] = carry_s;
}

__global__ void scatter_kernel(const int* __restrict__ ei, int* __restrict__ cursor,
                               int* __restrict__ csr_rows) {
  int e = blockIdx.x * blockDim.x + threadIdx.x;
  if (e < N_EDGES) {
    int c = ei[N_EDGES + e];
    int pos = atomicAdd(&cursor[c], 1);
    csr_rows[pos] = ei[e];
  }
}

// ---------------- node GEMM ----------------
// out[row][c] = sum_k A[row][k] * W[c*ldw + koff + k]  (+bias[c]) (+deg[row]*bias2[c]) (+=out if accum)
// tile 64 rows x 128 cols; K=128 in 2 chunks of 64; 256 threads; thread = 4 rows x 8 cols.
// LDS 50KB -> 3 blocks/CU. In-place (out==A) is safe: each block reads all its A rows
// (both k-chunks) before the epilogue writes, and blocks own disjoint rows.
__global__ __launch_bounds__(256, 3)
void gemm_kernel(const float* __restrict__ A, const float* __restrict__ W,
                 const float* __restrict__ bias, const int* __restrict__ deg,
                 const float* __restrict__ bias2, float* __restrict__ out,
                 int ldw, int koff, int accum) {
  __shared__ float Wt[64 * 132];  // [kk][c], stride 132: conflict-free b128 col reads
  __shared__ float As[64 * 68];   // [kk][row], stride 68: 2-way (free) b128 row reads
  const int tid = threadIdx.x;
  const int tr = tid & 15;   // rows tr*4 .. +3
  const int tc = tid >> 4;   // cols tc*8 .. +7
  const int r0 = blockIdx.x * 64;

  float acc[4][8];
#pragma unroll
  for (int i = 0; i < 4; ++i)
#pragma unroll
    for (int j = 0; j < 8; ++j) acc[i][j] = 0.f;

  for (int kc = 0; kc < 128; kc += 64) {
    __syncthreads();  // protect LDS from previous chunk's readers
    for (int u = tid; u < 64 * 128; u += 256) {  // W chunk, coalesced in k
      int kk = u & 63, c = u >> 6;
      Wt[kk * 132 + c] = W[(size_t)c * ldw + koff + kc + kk];
    }
    for (int u = tid; u < 64 * 64; u += 256) {   // A chunk, coalesced in k
      int kk = u & 63, row = u >> 6;
      int gr = r0 + row;
      As[kk * 68 + row] = (gr < N_NODES) ? A[(size_t)gr * HID + kc + kk] : 0.f;
    }
    __syncthreads();
#pragma unroll 4
    for (int kk = 0; kk < 64; ++kk) {
      float4 a4 = *(const float4*)&As[kk * 68 + tr * 4];
      float4 w0 = *(const float4*)&Wt[kk * 132 + tc * 8];
      float4 w1 = *(const float4*)&Wt[kk * 132 + tc * 8 + 4];
      float av[4] = {a4.x, a4.y, a4.z, a4.w};
      float wv[8] = {w0.x, w0.y, w0.z, w0.w, w1.x, w1.y, w1.z, w1.w};
#pragma unroll
      for (int i = 0; i < 4; ++i)
#pragma unroll
        for (int j = 0; j < 8; ++j) acc[i][j] = fmaf(av[i], wv[j], acc[i][j]);
    }
  }
#pragma unroll
  for (int i = 0; i < 4; ++i) {
    int row = r0 + tr * 4 + i;
    if (row >= N_NODES) continue;
    float* o = out + (size_t)row * HID + tc * 8;
    float dv = (deg != nullptr) ? (float)deg[row] : 0.f;
#pragma unroll
    for (int j = 0; j < 8; ++j) {
      float v = acc[i][j];
      if (bias) v += bias[tc * 8 + j];
      if (bias2) v += dv * bias2[tc * 8 + j];
      if (accum) v += o[j];
      o[j] = v;
    }
  }
}

// ---------------- edge aggregation: r[n] = sum_{e: col[e]=n} relu(p[row[e]] + q[n] + bm1) ----------------
__global__ void aggregate_kernel(const float* __restrict__ p, const float* __restrict__ q,
                                 const float* __restrict__ bm1,
                                 const int* __restrict__ offsets, const int* __restrict__ csr_rows,
                                 float* __restrict__ r) {
  int node = blockIdx.x * 2 + (threadIdx.x >> 7);
  if (node >= N_NODES) return;
  int c = threadIdx.x & 127;
  float qb = q[(size_t)node * HID + c] + bm1[c];
  float acc = 0.f;
  int i0 = offsets[node], i1 = offsets[node + 1];
  int idx = i0;
  for (; idx + 1 < i1; idx += 2) {
    int s0 = csr_rows[idx], s1 = csr_rows[idx + 1];
    float x0 = p[(size_t)s0 * HID + c] + qb;
    float x1 = p[(size_t)s1 * HID + c] + qb;
    acc += fmaxf(x0, 0.f) + fmaxf(x1, 0.f);
  }
  if (idx < i1) {
    int s0 = csr_rows[idx];
    acc += fmaxf(p[(size_t)s0 * HID + c] + qb, 0.f);
  }
  r[(size_t)node * HID + c] = acc;
}

// ---------------- residual + layernorm (in-place on h) ----------------
__global__ void ln_kernel(float* __restrict__ h, const float* __restrict__ upd,
                          const float* __restrict__ gamma, const float* __restrict__ beta) {
  int node = blockIdx.x * 4 + (threadIdx.x >> 6);
  int lane = threadIdx.x & 63;
  if (node >= N_NODES) return;
  size_t base = (size_t)node * HID;
  float v0 = h[base + lane] + upd[base + lane];
  float v1 = h[base + lane + 64] + upd[base + lane + 64];
  float s = v0 + v1, s2 = v0 * v0 + v1 * v1;
#pragma unroll
  for (int off = 32; off > 0; off >>= 1) {
    s += __shfl_xor(s, off);
    s2 += __shfl_xor(s2, off);
  }
  float mu = s * (1.f / 128.f);
  float var = s2 * (1.f / 128.f) - mu * mu;
  float inv = rsqrtf(var + EPS);
  h[base + lane] = (v0 - mu) * inv * gamma[lane] + beta[lane];
  h[base + lane + 64] = (v1 - mu) * inv * gamma[lane + 64] + beta[lane + 64];
}

extern "C" void kernel_launch(void* const* d_in, const int* in_sizes, int n_in,
                              void* d_out, int out_size, void* d_ws, size_t ws_size,
                              hipStream_t stream) {
  const float* x     = (const float*)d_in[0];
  const int*   ei    = (const int*)d_in[1];   // [2][E]: row=ei[e], col=ei[E+e]
  const float* W_enc = (const float*)d_in[2];
  const float* b_enc = (const float*)d_in[3];
  const float* Wm1   = (const float*)d_in[4]; // [2][128][256]
  const float* bm1   = (const float*)d_in[5];
  const float* Wm2   = (const float*)d_in[6]; // [2][128][128]
  const float* bm2   = (const float*)d_in[7];
  const float* Wu    = (const float*)d_in[8]; // [2][128][256]
  const float* bu    = (const float*)d_in[9];
  const float* gamma = (const float*)d_in[10];
  const float* beta  = (const float*)d_in[11];
  const float* W_out = (const float*)d_in[12];
  const float* b_out = (const float*)d_in[13];
  float* out = (float*)d_out;

  char* ws = (char*)d_ws;
  const size_t NB = (size_t)N_NODES * HID * sizeof(float);  // 25.6 MB
  float* h = (float*)(ws);
  float* p = (float*)(ws + NB);
  float* q = (float*)(ws + 2 * NB);
  int* counts  = (int*)(ws + 3 * NB);        // deg (kept intact)
  int* offsets = counts + N_NODES;           // N+1
  int* cursor  = offsets + N_NODES + 1;      // mutated by scatter
  int* csr     = cursor + N_NODES;           // [E] source rows grouped by col
  float* r = out;  // reuse d_out as agg scratch; final GEMM overwrites it

  hipMemsetAsync(counts, 0, N_NODES * sizeof(int), stream);
  hist_kernel<<<(N_EDGES + 255) / 256, 256, 0, stream>>>(ei, counts);
  scan_kernel<<<1, 1024, 0, stream>>>(counts, offsets, cursor);
  scatter_kernel<<<(N_EDGES + 255) / 256, 256, 0, stream>>>(ei, cursor, csr);

  const int GT = (N_NODES + 63) / 64;  // 782 row tiles

  // h = x @ W_enc.T + b_enc
  gemm_kernel<<<GT, 256, 0, stream>>>(x, W_enc, b_enc, nullptr, nullptr, h, HID, 0, 0);

  for (int l = 0; l < 2; ++l) {
    const float* Wm1l = Wm1 + (size_t)l * HID * 2 * HID;
    const float* Wm2l = Wm2 + (size_t)l * HID * HID;
    const float* Wul  = Wu  + (size_t)l * HID * 2 * HID;
    const float* bm1l = bm1 + l * HID;
    const float* bm2l = bm2 + l * HID;
    const float* bul  = bu  + l * HID;
    const float* gl   = gamma + l * HID;
    const float* bl   = beta + l * HID;

    // p = h @ Wm1[:, :128].T ; q = h @ Wm1[:, 128:].T   (bm1 added in aggregate)
    gemm_kernel<<<GT, 256, 0, stream>>>(h, Wm1l, nullptr, nullptr, nullptr, p, 2 * HID, 0, 0);
    gemm_kernel<<<GT, 256, 0, stream>>>(h, Wm1l, nullptr, nullptr, nullptr, q, 2 * HID, HID, 0);
    // r[n] = sum_{col[e]=n} relu(p[row[e]] + q[n] + bm1)
    aggregate_kernel<<<(N_NODES + 1) / 2, 256, 0, stream>>>(p, q, bm1l, offsets, csr, r);
    // agg = r @ Wm2.T + deg*bm2   (in-place on r)
    gemm_kernel<<<GT, 256, 0, stream>>>(r, Wm2l, nullptr, counts, bm2l, r, HID, 0, 0);
    // upd = h @ Wu[:, :128].T + bu ; upd += agg @ Wu[:, 128:].T
    gemm_kernel<<<GT, 256, 0, stream>>>(h, Wul, bul, nullptr, nullptr, p, 2 * HID, 0, 0);
    gemm_kernel<<<GT, 256, 0, stream>>>(r, Wul, nullptr, nullptr, nullptr, p, 2 * HID, HID, 1);
    // h = LN(h + upd) * gamma + beta
    ln_kernel<<<(N_NODES + 3) / 4, 256, 0, stream>>>(h, p, gl, bl);
  }

  // out = h @ W_out.T + b_out
  gemm_kernel<<<GT, 256, 0, stream>>>(h, W_out, b_out, nullptr, nullptr, out, HID, 0, 0);
}

// Round 3
// 1137.383 us; speedup vs baseline: 1.0046x; 1.0027x over previous
//
#include <hip/hip_runtime.h>

#define N_NODES 50000
#define N_EDGES 800000
#define HID 128
#define EPS 1e-5f

// ---------------- CSR build (once per launch; reused by both layers) ----------------
__global__ void hist_kernel(const int* __restrict__ ei, int* __restrict__ counts) {
  int e = blockIdx.x * blockDim.x + threadIdx.x;
  if (e < N_EDGES) atomicAdd(&counts[ei[N_EDGES + e]], 1);
}

// single block, 1024 threads: exclusive scan of counts -> offsets (and cursor copy)
__global__ void scan_kernel(const int* __restrict__ counts, int* __restrict__ offsets,
                            int* __restrict__ cursor) {
  __shared__ int wtot[16];
  __shared__ int carry_s;
  const int tid = threadIdx.x;
  const int lane = tid & 63, w = tid >> 6;
  if (tid == 0) carry_s = 0;
  __syncthreads();
  for (int base = 0; base < N_NODES; base += 1024) {
    int i = base + tid;
    int v = (i < N_NODES) ? counts[i] : 0;
    int s = v;
#pragma unroll
    for (int off = 1; off < 64; off <<= 1) {
      int t = __shfl_up(s, off);
      if (lane >= off) s += t;
    }
    if (lane == 63) wtot[w] = s;
    __syncthreads();                       // wtot visible
    int c0 = carry_s;
    int woff = 0;
    for (int j = 0; j < 16; ++j) { int t = wtot[j]; if (j < w) woff += t; }
    int excl = c0 + woff + (s - v);
    if (i < N_NODES) { offsets[i] = excl; cursor[i] = excl; }
    __syncthreads();                       // all c0/wtot reads done
    if (tid == 1023) carry_s = c0 + woff + s;  // chunk total appended
    __syncthreads();                       // carry visible before next iter
  }
  if (tid == 0) offsets[N_NODES] = carry_s;
}

__global__ void scatter_kernel(const int* __restrict__ ei, int* __restrict__ cursor,
                               int* __restrict__ csr_rows) {
  int e = blockIdx.x * blockDim.x + threadIdx.x;
  if (e < N_EDGES) {
    int c = ei[N_EDGES + e];
    int pos = atomicAdd(&cursor[c], 1);
    csr_rows[pos] = ei[e];
  }
}

// ---------------- node GEMM ----------------
// out[row][c] = sum_k A[row][k] * W[c*ldw + koff + k]  (+bias[c]) (+deg[row]*bias2[c]) (+=out if accum)
// tile 64 rows x 128 cols; K=128 in 2 chunks of 64; 256 threads; thread = 4 rows x 8 cols.
// LDS 50KB -> 3 blocks/CU. In-place (out==A) is safe: each block reads all its A rows
// (both k-chunks) before the epilogue writes, and blocks own disjoint rows.
__global__ __launch_bounds__(256, 3)
void gemm_kernel(const float* __restrict__ A, const float* __restrict__ W,
                 const float* __restrict__ bias, const int* __restrict__ deg,
                 const float* __restrict__ bias2, float* __restrict__ out,
                 int ldw, int koff, int accum) {
  __shared__ float Wt[64 * 132];  // [kk][c], stride 132: conflict-free b128 col reads
  __shared__ float As[64 * 68];   // [kk][row], stride 68: 2-way (free) b128 row reads
  const int tid = threadIdx.x;
  const int tr = tid & 15;   // rows tr*4 .. +3
  const int tc = tid >> 4;   // cols tc*8 .. +7
  const int r0 = blockIdx.x * 64;

  float acc[4][8];
#pragma unroll
  for (int i = 0; i < 4; ++i)
#pragma unroll
    for (int j = 0; j < 8; ++j) acc[i][j] = 0.f;

  for (int kc = 0; kc < 128; kc += 64) {
    __syncthreads();  // protect LDS from previous chunk's readers
    for (int u = tid; u < 64 * 128; u += 256) {  // W chunk, coalesced in k
      int kk = u & 63, c = u >> 6;
      Wt[kk * 132 + c] = W[(size_t)c * ldw + koff + kc + kk];
    }
    for (int u = tid; u < 64 * 64; u += 256) {   // A chunk, coalesced in k
      int kk = u & 63, row = u >> 6;
      int gr = r0 + row;
      As[kk * 68 + row] = (gr < N_NODES) ? A[(size_t)gr * HID + kc + kk] : 0.f;
    }
    __syncthreads();
#pragma unroll 4
    for (int kk = 0; kk < 64; ++kk) {
      float4 a4 = *(const float4*)&As[kk * 68 + tr * 4];
      float4 w0 = *(const float4*)&Wt[kk * 132 + tc * 8];
      float4 w1 = *(const float4*)&Wt[kk * 132 + tc * 8 + 4];
      float av[4] = {a4.x, a4.y, a4.z, a4.w};
      float wv[8] = {w0.x, w0.y, w0.z, w0.w, w1.x, w1.y, w1.z, w1.w};
#pragma unroll
      for (int i = 0; i < 4; ++i)
#pragma unroll
        for (int j = 0; j < 8; ++j) acc[i][j] = fmaf(av[i], wv[j], acc[i][j]);
    }
  }
#pragma unroll
  for (int i = 0; i < 4; ++i) {
    int row = r0 + tr * 4 + i;
    if (row >= N_NODES) continue;
    float* o = out + (size_t)row * HID + tc * 8;
    float dv = (deg != nullptr) ? (float)deg[row] : 0.f;
#pragma unroll
    for (int j = 0; j < 8; ++j) {
      float v = acc[i][j];
      if (bias) v += bias[tc * 8 + j];
      if (bias2) v += dv * bias2[tc * 8 + j];
      if (accum) v += o[j];
      o[j] = v;
    }
  }
}

// ---------------- edge aggregation: r[n] = sum_{e: col[e]=n} relu(p[row[e]] + q[n] + bm1) ----------------
__global__ void aggregate_kernel(const float* __restrict__ p, const float* __restrict__ q,
                                 const float* __restrict__ bm1,
                                 const int* __restrict__ offsets, const int* __restrict__ csr_rows,
                                 float* __restrict__ r) {
  int node = blockIdx.x * 2 + (threadIdx.x >> 7);
  if (node >= N_NODES) return;
  int c = threadIdx.x & 127;
  float qb = q[(size_t)node * HID + c] + bm1[c];
  float acc = 0.f;
  int i0 = offsets[node], i1 = offsets[node + 1];
  int idx = i0;
  for (; idx + 1 < i1; idx += 2) {
    int s0 = csr_rows[idx], s1 = csr_rows[idx + 1];
    float x0 = p[(size_t)s0 * HID + c] + qb;
    float x1 = p[(size_t)s1 * HID + c] + qb;
    acc += fmaxf(x0, 0.f) + fmaxf(x1, 0.f);
  }
  if (idx < i1) {
    int s0 = csr_rows[idx];
    acc += fmaxf(p[(size_t)s0 * HID + c] + qb, 0.f);
  }
  r[(size_t)node * HID + c] = acc;
}

// ---------------- residual + layernorm (in-place on h) ----------------
__global__ void ln_kernel(float* __restrict__ h, const float* __restrict__ upd,
                          const float* __restrict__ gamma, const float* __restrict__ beta) {
  int node = blockIdx.x * 4 + (threadIdx.x >> 6);
  int lane = threadIdx.x & 63;
  if (node >= N_NODES) return;
  size_t base = (size_t)node * HID;
  float v0 = h[base + lane] + upd[base + lane];
  float v1 = h[base + lane + 64] + upd[base + lane + 64];
  float s = v0 + v1, s2 = v0 * v0 + v1 * v1;
#pragma unroll
  for (int off = 32; off > 0; off >>= 1) {
    s += __shfl_xor(s, off);
    s2 += __shfl_xor(s2, off);
  }
  float mu = s * (1.f / 128.f);
  float var = s2 * (1.f / 128.f) - mu * mu;
  float inv = rsqrtf(var + EPS);
  h[base + lane] = (v0 - mu) * inv * gamma[lane] + beta[lane];
  h[base + lane + 64] = (v1 - mu) * inv * gamma[lane + 64] + beta[lane + 64];
}

extern "C" void kernel_launch(void* const* d_in, const int* in_sizes, int n_in,
                              void* d_out, int out_size, void* d_ws, size_t ws_size,
                              hipStream_t stream) {
  const float* x     = (const float*)d_in[0];
  const int*   ei    = (const int*)d_in[1];   // [2][E]: row=ei[e], col=ei[E+e]
  const float* W_enc = (const float*)d_in[2];
  const float* b_enc = (const float*)d_in[3];
  const float* Wm1   = (const float*)d_in[4]; // [2][128][256]
  const float* bm1   = (const float*)d_in[5];
  const float* Wm2   = (const float*)d_in[6]; // [2][128][128]
  const float* bm2   = (const float*)d_in[7];
  const float* Wu    = (const float*)d_in[8]; // [2][128][256]
  const float* bu    = (const float*)d_in[9];
  const float* gamma = (const float*)d_in[10];
  const float* beta  = (const float*)d_in[11];
  const float* W_out = (const float*)d_in[12];
  const float* b_out = (const float*)d_in[13];
  float* out = (float*)d_out;

  char* ws = (char*)d_ws;
  const size_t NB = (size_t)N_NODES * HID * sizeof(float);  // 25.6 MB
  float* h = (float*)(ws);
  float* p = (float*)(ws + NB);
  float* q = (float*)(ws + 2 * NB);
  int* counts  = (int*)(ws + 3 * NB);        // deg (kept intact)
  int* offsets = counts + N_NODES;           // N+1
  int* cursor  = offsets + N_NODES + 1;      // mutated by scatter
  int* csr     = cursor + N_NODES;           // [E] source rows grouped by col
  float* r = out;  // reuse d_out as agg scratch; final GEMM overwrites it

  hipMemsetAsync(counts, 0, N_NODES * sizeof(int), stream);
  hist_kernel<<<(N_EDGES + 255) / 256, 256, 0, stream>>>(ei, counts);
  scan_kernel<<<1, 1024, 0, stream>>>(counts, offsets, cursor);
  scatter_kernel<<<(N_EDGES + 255) / 256, 256, 0, stream>>>(ei, cursor, csr);

  const int GT = (N_NODES + 63) / 64;  // 782 row tiles

  // h = x @ W_enc.T + b_enc
  gemm_kernel<<<GT, 256, 0, stream>>>(x, W_enc, b_enc, nullptr, nullptr, h, HID, 0, 0);

  for (int l = 0; l < 2; ++l) {
    const float* Wm1l = Wm1 + (size_t)l * HID * 2 * HID;
    const float* Wm2l = Wm2 + (size_t)l * HID * HID;
    const float* Wul  = Wu  + (size_t)l * HID * 2 * HID;
    const float* bm1l = bm1 + l * HID;
    const float* bm2l = bm2 + l * HID;
    const float* bul  = bu  + l * HID;
    const float* gl   = gamma + l * HID;
    const float* bl   = beta + l * HID;

    // p = h @ Wm1[:, :128].T ; q = h @ Wm1[:, 128:].T   (bm1 added in aggregate)
    gemm_kernel<<<GT, 256, 0, stream>>>(h, Wm1l, nullptr, nullptr, nullptr, p, 2 * HID, 0, 0);
    gemm_kernel<<<GT, 256, 0, stream>>>(h, Wm1l, nullptr, nullptr, nullptr, q, 2 * HID, HID, 0);
    // r[n] = sum_{col[e]=n} relu(p[row[e]] + q[n] + bm1)
    aggregate_kernel<<<(N_NODES + 1) / 2, 256, 0, stream>>>(p, q, bm1l, offsets, csr, r);
    // agg = r @ Wm2.T + deg*bm2   (in-place on r)
    gemm_kernel<<<GT, 256, 0, stream>>>(r, Wm2l, nullptr, counts, bm2l, r, HID, 0, 0);
    // upd = h @ Wu[:, :128].T + bu ; upd += agg @ Wu[:, 128:].T
    gemm_kernel<<<GT, 256, 0, stream>>>(h, Wul, bul, nullptr, nullptr, p, 2 * HID, 0, 0);
    gemm_kernel<<<GT, 256, 0, stream>>>(r, Wul, nullptr, nullptr, nullptr, p, 2 * HID, HID, 1);
    // h = LN(h + upd) * gamma + beta
    ln_kernel<<<(N_NODES + 3) / 4, 256, 0, stream>>>(h, p, gl, bl);
  }

  // out = h @ W_out.T + b_out
  gemm_kernel<<<GT, 256, 0, stream>>>(h, W_out, b_out, nullptr, nullptr, out, HID, 0, 0);
}

// Round 4
// 522.891 us; speedup vs baseline: 2.1852x; 2.1752x over previous
//
#include <hip/hip_runtime.h>

#define N_NODES 50000
#define N_EDGES 800000
#define HID 128
#define EPS 1e-5f

typedef __attribute__((ext_vector_type(8))) short s16x8;   // 8 bf16 (4 VGPRs)
typedef __attribute__((ext_vector_type(4))) float f32x4;   // MFMA acc

__device__ __forceinline__ unsigned short f2bf(float f) {  // RNE f32->bf16
  unsigned int u = __float_as_uint(f);
  u += 0x7fffu + ((u >> 16) & 1u);
  return (unsigned short)(u >> 16);
}
__device__ __forceinline__ unsigned int pack2(float a, float b) {
  return (unsigned int)f2bf(a) | ((unsigned int)f2bf(b) << 16);
}
__device__ __forceinline__ float bflo(unsigned int u) { return __uint_as_float(u << 16); }
__device__ __forceinline__ float bfhi(unsigned int u) { return __uint_as_float(u & 0xffff0000u); }

// ---------------- CSR build ----------------
__global__ void hist_kernel(const int* __restrict__ ei, int* __restrict__ counts) {
  int e = blockIdx.x * blockDim.x + threadIdx.x;
  if (e < N_EDGES) atomicAdd(&counts[ei[N_EDGES + e]], 1);
}

__global__ void scan_kernel(const int* __restrict__ counts, int* __restrict__ offsets,
                            int* __restrict__ cursor) {
  __shared__ int wtot[16];
  __shared__ int carry_s;
  const int tid = threadIdx.x;
  const int lane = tid & 63, w = tid >> 6;
  if (tid == 0) carry_s = 0;
  __syncthreads();
  for (int base = 0; base < N_NODES; base += 1024) {
    int i = base + tid;
    int v = (i < N_NODES) ? counts[i] : 0;
    int s = v;
#pragma unroll
    for (int off = 1; off < 64; off <<= 1) {
      int t = __shfl_up(s, off);
      if (lane >= off) s += t;
    }
    if (lane == 63) wtot[w] = s;
    __syncthreads();
    int c0 = carry_s;
    int woff = 0;
    for (int j = 0; j < 16; ++j) { int t = wtot[j]; if (j < w) woff += t; }
    int excl = c0 + woff + (s - v);
    if (i < N_NODES) { offsets[i] = excl; cursor[i] = excl; }
    __syncthreads();
    if (tid == 1023) carry_s = c0 + woff + s;
    __syncthreads();
  }
  if (tid == 0) offsets[N_NODES] = carry_s;
}

__global__ void scatter_kernel(const int* __restrict__ ei, int* __restrict__ cursor,
                               int* __restrict__ csr_rows) {
  int e = blockIdx.x * blockDim.x + threadIdx.x;
  if (e < N_EDGES) {
    int c = ei[N_EDGES + e];
    int pos = atomicAdd(&cursor[c], 1);
    csr_rows[pos] = ei[e];
  }
}

// ---------------- converters ----------------
__global__ void convert_f32_bf16(const float* __restrict__ src, unsigned int* __restrict__ dst,
                                 int n2) {
  int i = blockIdx.x * blockDim.x + threadIdx.x;
  if (i < n2) {
    float2 v = *(const float2*)(src + 2 * (size_t)i);
    dst[i] = pack2(v.x, v.y);
  }
}

// Wpq[l][c][k] = Wm1[l][c&127][(c>>7)*128 + k]  (c<128 -> p-part, c>=128 -> q-part)
__global__ void repack_wpq(const float* __restrict__ Wm1, unsigned int* __restrict__ dst) {
  int i = blockIdx.x * blockDim.x + threadIdx.x;  // 2*256*64 uint outputs
  if (i >= 2 * 256 * 64) return;
  int k2 = i & 63;
  int c = (i >> 6) & 255;
  int l = i >> 14;
  const float* srow = Wm1 + ((size_t)l * 128 + (c & 127)) * 256 + ((c >> 7) << 7);
  dst[i] = pack2(srow[2 * k2], srow[2 * k2 + 1]);
}

// ---------------- MFMA GEMM (no LDS; B is L1/L2-hot) ----------------
// out[row][c] = sum_k A[row][k]*W[c][k] (+bias[c]) (+deg[row]*bias2[c])
// A rows are HID=128 bf16. DUAL: K=256, k<128 from A0, k>=128 from A1 (W rows are 256 long).
// Block = 256 thr = 4 waves; wave owns 16 rows; NT 16-col tiles; KS k-steps of 32.
// In-place (out==A) is safe: each wave's A-row set == its store-row set, loads precede stores.
template <int NT, int KS, bool DUAL, int STORE>
__global__ __launch_bounds__(256) void mfma_gemm(
    const unsigned short* __restrict__ A0, const unsigned short* __restrict__ A1,
    const unsigned short* __restrict__ W, const float* __restrict__ bias,
    const int* __restrict__ deg, const float* __restrict__ bias2,
    float* __restrict__ outF, unsigned short* __restrict__ outB) {
  const int lane = threadIdx.x & 63;
  const int w = threadIdx.x >> 6;
  const int r0 = blockIdx.x * 64 + w * 16;
  const int cl = lane & 15;
  const int kb = (lane >> 4) * 8;
  const int KW = KS * 32;  // W row length

  int arow = r0 + cl;
  if (arow > N_NODES - 1) arow = N_NODES - 1;  // clamp loads; stores guarded

  f32x4 acc[NT];
#pragma unroll
  for (int i = 0; i < NT; ++i) acc[i] = (f32x4){0.f, 0.f, 0.f, 0.f};

#pragma unroll
  for (int ks = 0; ks < KS; ++ks) {
    s16x8 a;
    if constexpr (DUAL) {
      if (ks < KS / 2)
        a = *(const s16x8*)(A0 + (size_t)arow * HID + ks * 32 + kb);
      else
        a = *(const s16x8*)(A1 + (size_t)arow * HID + (ks - KS / 2) * 32 + kb);
    } else {
      a = *(const s16x8*)(A0 + (size_t)arow * HID + ks * 32 + kb);
    }
#pragma unroll
    for (int nt = 0; nt < NT; ++nt) {
      s16x8 b = *(const s16x8*)(W + (size_t)(nt * 16 + cl) * KW + ks * 32 + kb);
      acc[nt] = __builtin_amdgcn_mfma_f32_16x16x32_bf16(a, b, acc[nt], 0, 0, 0);
    }
  }

  // epilogue: C/D layout col = lane&15 (+16*nt), row = (lane>>4)*4 + reg
  float bs[NT], b2s[NT];
#pragma unroll
  for (int nt = 0; nt < NT; ++nt) {
    int col = nt * 16 + cl;
    bs[nt] = bias ? bias[col] : 0.f;
    b2s[nt] = bias2 ? bias2[col] : 0.f;
  }
  const int rb = r0 + (lane >> 4) * 4;
#pragma unroll
  for (int reg = 0; reg < 4; ++reg) {
    int row = rb + reg;
    if (row < N_NODES) {
      float dv = deg ? (float)deg[row] : 0.f;
#pragma unroll
      for (int nt = 0; nt < NT; ++nt) {
        int col = nt * 16 + cl;
        float v = acc[nt][reg] + bs[nt] + dv * b2s[nt];
        if constexpr (STORE & 1) outF[(size_t)row * (NT * 16) + col] = v;
        if constexpr (STORE & 2) outB[(size_t)row * (NT * 16) + col] = f2bf(v);
      }
    }
  }
}

// ---------------- edge aggregation (bf16 gather) ----------------
// r[n] = sum_{e: col[e]=n} relu(p[src] + q[n] + bm1);  pq = [N][256] bf16 (p|q)
__global__ __launch_bounds__(256) void aggregate_kernel(
    const unsigned int* __restrict__ pq32, const float* __restrict__ bm1,
    const int* __restrict__ offsets, const int* __restrict__ csr,
    unsigned int* __restrict__ rb32) {
  int node = blockIdx.x * 4 + (threadIdx.x >> 6);
  if (node >= N_NODES) return;
  int lane = threadIdx.x & 63;
  unsigned int qu = pq32[(size_t)node * 128 + 64 + lane];
  float q0 = bflo(qu) + bm1[2 * lane];
  float q1 = bfhi(qu) + bm1[2 * lane + 1];
  float a0 = 0.f, a1 = 0.f;
  int i0 = offsets[node], i1 = offsets[node + 1];
  int idx = i0;
  for (; idx + 1 < i1; idx += 2) {
    int s0 = csr[idx], s1 = csr[idx + 1];
    unsigned int u0 = pq32[(size_t)s0 * 128 + lane];
    unsigned int u1 = pq32[(size_t)s1 * 128 + lane];
    a0 += fmaxf(bflo(u0) + q0, 0.f) + fmaxf(bflo(u1) + q0, 0.f);
    a1 += fmaxf(bfhi(u0) + q1, 0.f) + fmaxf(bfhi(u1) + q1, 0.f);
  }
  if (idx < i1) {
    unsigned int u0 = pq32[(size_t)csr[idx] * 128 + lane];
    a0 += fmaxf(bflo(u0) + q0, 0.f);
    a1 += fmaxf(bfhi(u0) + q1, 0.f);
  }
  rb32[(size_t)node * 64 + lane] = pack2(a0, a1);
}

// ---------------- residual + LN: h = LN(h+upd); writes h (f32) and hb (bf16) ----------------
__global__ __launch_bounds__(256) void ln_kernel(
    float* __restrict__ h, const float* __restrict__ upd, const float* __restrict__ gamma,
    const float* __restrict__ beta, unsigned int* __restrict__ hb32) {
  int node = blockIdx.x * 4 + (threadIdx.x >> 6);
  if (node >= N_NODES) return;
  int lane = threadIdx.x & 63;
  size_t base = (size_t)node * HID + 2 * lane;
  float2 hv = *(const float2*)&h[base];
  float2 uv = *(const float2*)&upd[base];
  float v0 = hv.x + uv.x, v1 = hv.y + uv.y;
  float s = v0 + v1, s2 = v0 * v0 + v1 * v1;
#pragma unroll
  for (int off = 32; off > 0; off >>= 1) {
    s += __shfl_xor(s, off);
    s2 += __shfl_xor(s2, off);
  }
  float mu = s * (1.f / 128.f);
  float var = s2 * (1.f / 128.f) - mu * mu;
  float inv = rsqrtf(var + EPS);
  float2 g = *(const float2*)&gamma[2 * lane];
  float2 be = *(const float2*)&beta[2 * lane];
  float o0 = (v0 - mu) * inv * g.x + be.x;
  float o1 = (v1 - mu) * inv * g.y + be.y;
  *(float2*)&h[base] = make_float2(o0, o1);
  hb32[(size_t)node * 64 + lane] = pack2(o0, o1);
}

extern "C" void kernel_launch(void* const* d_in, const int* in_sizes, int n_in,
                              void* d_out, int out_size, void* d_ws, size_t ws_size,
                              hipStream_t stream) {
  const float* x     = (const float*)d_in[0];
  const int*   ei    = (const int*)d_in[1];
  const float* W_enc = (const float*)d_in[2];
  const float* b_enc = (const float*)d_in[3];
  const float* Wm1   = (const float*)d_in[4];  // [2][128][256]
  const float* bm1   = (const float*)d_in[5];
  const float* Wm2   = (const float*)d_in[6];  // [2][128][128]
  const float* bm2   = (const float*)d_in[7];
  const float* Wu    = (const float*)d_in[8];  // [2][128][256]
  const float* bu    = (const float*)d_in[9];
  const float* gamma = (const float*)d_in[10];
  const float* beta  = (const float*)d_in[11];
  const float* W_out = (const float*)d_in[12];
  const float* b_out = (const float*)d_in[13];
  float* out = (float*)d_out;

  char* ws = (char*)d_ws;
  const size_t NB  = (size_t)N_NODES * HID * 4;  // 25.6 MB (f32 node array)
  const size_t NBH = (size_t)N_NODES * HID * 2;  // 12.8 MB (bf16 node array)

  float*          h     = (float*)(ws);
  char*           pbuf  = ws + NB;            // shared 25.6MB: xb | pq | upd
  unsigned short* xb    = (unsigned short*)pbuf;
  unsigned short* pq    = (unsigned short*)pbuf;
  float*          updF  = (float*)pbuf;
  unsigned short* hb    = (unsigned short*)(ws + 2 * NB);
  unsigned short* rb    = (unsigned short*)(ws + 2 * NB + NBH);
  unsigned short* wts   = (unsigned short*)(ws + 2 * NB + 2 * NBH);
  unsigned short* Wenc_b = wts;               // 16384
  unsigned short* Wout_b = Wenc_b + 16384;    // 16384
  unsigned short* Wm2_b  = Wout_b + 16384;    // 2*16384
  unsigned short* Wu_b   = Wm2_b + 32768;     // 2*32768
  unsigned short* Wpq_b  = Wu_b + 65536;      // 2*32768
  int* counts  = (int*)(Wpq_b + 65536);
  int* offsets = counts + N_NODES;
  int* cursor  = offsets + N_NODES + 1;
  int* csr     = cursor + N_NODES;

  // CSR build
  hipMemsetAsync(counts, 0, N_NODES * sizeof(int), stream);
  hist_kernel<<<(N_EDGES + 255) / 256, 256, 0, stream>>>(ei, counts);
  scan_kernel<<<1, 1024, 0, stream>>>(counts, offsets, cursor);
  scatter_kernel<<<(N_EDGES + 255) / 256, 256, 0, stream>>>(ei, cursor, csr);

  // converts
  convert_f32_bf16<<<12500, 256, 0, stream>>>(x, (unsigned int*)xb, N_NODES * HID / 2);
  convert_f32_bf16<<<32, 256, 0, stream>>>(W_enc, (unsigned int*)Wenc_b, 8192);
  convert_f32_bf16<<<32, 256, 0, stream>>>(W_out, (unsigned int*)Wout_b, 8192);
  convert_f32_bf16<<<64, 256, 0, stream>>>(Wm2, (unsigned int*)Wm2_b, 16384);
  convert_f32_bf16<<<128, 256, 0, stream>>>(Wu, (unsigned int*)Wu_b, 32768);
  repack_wpq<<<128, 256, 0, stream>>>(Wm1, (unsigned int*)Wpq_b);

  const int GT = (N_NODES + 63) / 64;  // 782

  // h = x @ W_enc.T + b_enc  -> f32 h + bf16 hb
  mfma_gemm<8, 4, false, 3><<<GT, 256, 0, stream>>>(xb, nullptr, Wenc_b, b_enc, nullptr,
                                                    nullptr, h, hb);

  for (int l = 0; l < 2; ++l) {
    const unsigned short* Wpql = Wpq_b + l * 32768;
    const unsigned short* Wm2l = Wm2_b + l * 16384;
    const unsigned short* Wul  = Wu_b + l * 32768;
    const float* bm1l = bm1 + l * HID;
    const float* bm2l = bm2 + l * HID;
    const float* bul  = bu + l * HID;
    const float* gl   = gamma + l * HID;
    const float* bl   = beta + l * HID;

    // pq = h @ [Wm1a|Wm1b].T  (bf16, [N][256])
    mfma_gemm<16, 4, false, 2><<<GT, 256, 0, stream>>>(hb, nullptr, Wpql, nullptr, nullptr,
                                                       nullptr, nullptr, pq);
    // r = segment-sum of relu(p[src]+q[dst]+bm1)  (bf16)
    aggregate_kernel<<<12500, 256, 0, stream>>>((const unsigned int*)pq, bm1l, offsets, csr,
                                                (unsigned int*)rb);
    // agg = r @ Wm2.T + deg*bm2  (in-place bf16)
    mfma_gemm<8, 4, false, 2><<<GT, 256, 0, stream>>>(rb, nullptr, Wm2l, nullptr, counts,
                                                      bm2l, nullptr, rb);
    // upd = [h|agg] @ Wu.T + bu  (f32, into pbuf)
    mfma_gemm<8, 8, true, 1><<<GT, 256, 0, stream>>>(hb, rb, Wul, bul, nullptr, nullptr,
                                                     updF, nullptr);
    // h = LN(h+upd)*gamma+beta  -> f32 h + bf16 hb
    ln_kernel<<<12500, 256, 0, stream>>>(h, updF, gl, bl, (unsigned int*)hb);
  }

  // out = h @ W_out.T + b_out
  mfma_gemm<8, 4, false, 1><<<GT, 256, 0, stream>>>(hb, nullptr, Wout_b, b_out, nullptr,
                                                    nullptr, out, nullptr);
}

// Round 5
// 333.102 us; speedup vs baseline: 3.4303x; 1.5698x over previous
//
#include <hip/hip_runtime.h>

#define N_NODES 50000
#define N_EDGES 800000
#define HID 128
#define EPS 1e-5f

typedef __attribute__((ext_vector_type(8))) short s16x8;   // 8 bf16 (4 VGPRs)
typedef __attribute__((ext_vector_type(4))) float f32x4;   // MFMA acc
typedef __attribute__((ext_vector_type(4))) int i32x4;

__device__ __forceinline__ unsigned short f2bf(float f) {  // RNE f32->bf16
  unsigned int u = __float_as_uint(f);
  u += 0x7fffu + ((u >> 16) & 1u);
  return (unsigned short)(u >> 16);
}
__device__ __forceinline__ unsigned int pack2(float a, float b) {
  return (unsigned int)f2bf(a) | ((unsigned int)f2bf(b) << 16);
}
__device__ __forceinline__ float bflo(unsigned int u) { return __uint_as_float(u << 16); }
__device__ __forceinline__ float bfhi(unsigned int u) { return __uint_as_float(u & 0xffff0000u); }
__device__ __forceinline__ float bf2f(unsigned short u) { return __uint_as_float((unsigned int)u << 16); }

// ---------------- CSR build ----------------
__global__ void hist_kernel(const int* __restrict__ ei, int* __restrict__ counts) {
  int e = blockIdx.x * blockDim.x + threadIdx.x;
  if (e < N_EDGES) atomicAdd(&counts[ei[N_EDGES + e]], 1);
}

__global__ void scan_kernel(const int* __restrict__ counts, int* __restrict__ offsets,
                            int* __restrict__ cursor) {
  __shared__ int wtot[16];
  __shared__ int carry_s;
  const int tid = threadIdx.x;
  const int lane = tid & 63, w = tid >> 6;
  if (tid == 0) carry_s = 0;
  __syncthreads();
  for (int base = 0; base < N_NODES; base += 1024) {
    int i = base + tid;
    int v = (i < N_NODES) ? counts[i] : 0;
    int s = v;
#pragma unroll
    for (int off = 1; off < 64; off <<= 1) {
      int t = __shfl_up(s, off);
      if (lane >= off) s += t;
    }
    if (lane == 63) wtot[w] = s;
    __syncthreads();
    int c0 = carry_s;
    int woff = 0;
    for (int j = 0; j < 16; ++j) { int t = wtot[j]; if (j < w) woff += t; }
    int excl = c0 + woff + (s - v);
    if (i < N_NODES) { offsets[i] = excl; cursor[i] = excl; }
    __syncthreads();
    if (tid == 1023) carry_s = c0 + woff + s;
    __syncthreads();
  }
  if (tid == 0) offsets[N_NODES] = carry_s;
}

__global__ void scatter_kernel(const int* __restrict__ ei, int* __restrict__ cursor,
                               int* __restrict__ csr_rows) {
  int e = blockIdx.x * blockDim.x + threadIdx.x;
  if (e < N_EDGES) {
    int c = ei[N_EDGES + e];
    int pos = atomicAdd(&cursor[c], 1);
    csr_rows[pos] = ei[e];
  }
}

// ---------------- weight prep ----------------
__global__ void convert_f32_bf16(const float* __restrict__ src, unsigned int* __restrict__ dst,
                                 int n2) {
  int i = blockIdx.x * blockDim.x + threadIdx.x;
  if (i < n2) {
    float2 v = *(const float2*)(src + 2 * (size_t)i);
    dst[i] = pack2(v.x, v.y);
  }
}

// Wpq[l][c][k] = Wm1[l][c&127][(c>>7)*128 + k]
__global__ void repack_wpq(const float* __restrict__ Wm1, unsigned int* __restrict__ dst) {
  int i = blockIdx.x * blockDim.x + threadIdx.x;  // 2*256*64
  if (i >= 2 * 256 * 64) return;
  int k2 = i & 63;
  int c = (i >> 6) & 255;
  int l = i >> 14;
  const float* srow = Wm1 + ((size_t)l * 128 + (c & 127)) * 256 + ((c >> 7) << 7);
  dst[i] = pack2(srow[2 * k2], srow[2 * k2 + 1]);
}

// Wcat[l][c][k]: k<128 -> Wu[l][c][k];  k>=128 -> sum_j Wu[l][c][128+j]*Wm2[l][j][k-128]
__global__ void fold_kernel(const float* __restrict__ Wu, const float* __restrict__ Wm2,
                            unsigned short* __restrict__ Wcat) {
  int i = blockIdx.x * 256 + threadIdx.x;  // 2*128*256
  if (i >= 2 * 128 * 256) return;
  int k = i & 255, c = (i >> 8) & 127, l = i >> 15;
  const float* wrow = Wu + ((size_t)l * 128 + c) * 256;
  float v;
  if (k < 128) {
    v = wrow[k];
  } else {
    const float* wb = wrow + 128;
    const float* m2 = Wm2 + (size_t)l * 128 * 128 + (k - 128);
    float s = 0.f;
    for (int j = 0; j < 128; ++j) s += wb[j] * m2[(size_t)j * 128];
    v = s;
  }
  Wcat[i] = f2bf(v);
}

// bfold[l][c] = sum_j Wu[l][c][128+j] * bm2[l][j]
__global__ void bfold_kernel(const float* __restrict__ Wu, const float* __restrict__ bm2,
                             float* __restrict__ bfold) {
  int i = threadIdx.x;  // 256
  int l = i >> 7, c = i & 127;
  const float* wb = Wu + ((size_t)l * 128 + c) * 256 + 128;
  const float* b = bm2 + l * 128;
  float s = 0.f;
  for (int j = 0; j < 128; ++j) s += wb[j] * b[j];
  bfold[i] = s;
}

// ---------------- MFMA GEMM: B staged once to LDS in fragment-linear order ----------------
// 782 blocks x 4 waves; wave = one 16-row tile (50000 = 3125*16 exactly).
// MODE 0: f32 out + bias.  MODE 1: bf16 out + bias.
// MODE 2: fused update+residual+LN: out = LN(hres + acc + bias + deg*bias2)*gamma+beta -> bf16.
//   In-place on hb is safe: each wave's load-row set == its store-row set; stores depend on
//   all MFMA A-loads via acc; waves/blocks own disjoint 16-row tiles.
template <int NT, int KS, bool AF32, bool DUAL, int MODE>
__global__ __launch_bounds__(256) void mfma_gemm(
    const void* __restrict__ A0v, const unsigned short* __restrict__ A1,
    const unsigned short* __restrict__ W, const float* __restrict__ bias,
    const int* __restrict__ deg, const float* __restrict__ bias2,
    const float* __restrict__ gamma, const float* __restrict__ beta,
    const unsigned short* __restrict__ hres, float* __restrict__ outF,
    unsigned short* __restrict__ outB) {
  constexpr int KW = KS * 32;
  constexpr int NFRAG = NT * KS;
  __shared__ short Bs[NFRAG * 512];  // frag f at Bs[f*512 + lane*8]: lane-linear, conflict-free
  const int lane = threadIdx.x & 63;
  const int w = threadIdx.x >> 6;
  const int cl = lane & 15;
  const int kb = (lane >> 4) * 8;

  for (int f = w; f < NFRAG; f += 4) {
    int nt = f % NT, ks = f / NT;
    s16x8 b = *(const s16x8*)(W + (size_t)(nt * 16 + cl) * KW + ks * 32 + kb);
    *(s16x8*)(Bs + f * 512 + lane * 8) = b;
  }
  __syncthreads();

  const int rt = blockIdx.x * 4 + w;
  if (rt * 16 >= N_NODES) return;
  const int arow = rt * 16 + cl;

  f32x4 acc[NT];
#pragma unroll
  for (int i = 0; i < NT; ++i) acc[i] = (f32x4){0.f, 0.f, 0.f, 0.f};

#pragma unroll
  for (int ks = 0; ks < KS; ++ks) {
    s16x8 a;
    if constexpr (AF32) {
      const float* ap = (const float*)A0v + (size_t)arow * HID + ks * 32 + kb;
      float4 lo = *(const float4*)ap;
      float4 hi = *(const float4*)(ap + 4);
      i32x4 ai = {(int)pack2(lo.x, lo.y), (int)pack2(lo.z, lo.w),
                  (int)pack2(hi.x, hi.y), (int)pack2(hi.z, hi.w)};
      a = __builtin_bit_cast(s16x8, ai);
    } else if constexpr (DUAL) {
      const unsigned short* base = (ks < KS / 2) ? (const unsigned short*)A0v : A1;
      int kss = (ks < KS / 2) ? ks : ks - KS / 2;
      a = *(const s16x8*)(base + (size_t)arow * HID + kss * 32 + kb);
    } else {
      a = *(const s16x8*)((const unsigned short*)A0v + (size_t)arow * HID + ks * 32 + kb);
    }
#pragma unroll
    for (int nt = 0; nt < NT; ++nt) {
      s16x8 b = *(const s16x8*)(Bs + (ks * NT + nt) * 512 + lane * 8);
      acc[nt] = __builtin_amdgcn_mfma_f32_16x16x32_bf16(a, b, acc[nt], 0, 0, 0);
    }
  }

  const int rbase = rt * 16 + (lane >> 4) * 4;
  float bs[NT];
#pragma unroll
  for (int nt = 0; nt < NT; ++nt) bs[nt] = bias ? bias[nt * 16 + cl] : 0.f;

  if constexpr (MODE == 2) {
    float b2[NT], gs[NT], bes[NT];
#pragma unroll
    for (int nt = 0; nt < NT; ++nt) {
      int col = nt * 16 + cl;
      b2[nt] = bias2[col];
      gs[nt] = gamma[col];
      bes[nt] = beta[col];
    }
#pragma unroll
    for (int reg = 0; reg < 4; ++reg) {
      int row = rbase + reg;
      float dv = (float)deg[row];
      float v[NT];
      float s = 0.f, s2 = 0.f;
#pragma unroll
      for (int nt = 0; nt < NT; ++nt) {
        int col = nt * 16 + cl;
        float hv = bf2f(hres[(size_t)row * HID + col]);
        v[nt] = acc[nt][reg] + bs[nt] + dv * b2[nt] + hv;
        s += v[nt];
        s2 += v[nt] * v[nt];
      }
#pragma unroll
      for (int m = 1; m < 16; m <<= 1) {
        s += __shfl_xor(s, m);
        s2 += __shfl_xor(s2, m);
      }
      float mu = s * (1.f / 128.f);
      float var = s2 * (1.f / 128.f) - mu * mu;
      float inv = rsqrtf(var + EPS);
#pragma unroll
      for (int nt = 0; nt < NT; ++nt) {
        float o = (v[nt] - mu) * inv * gs[nt] + bes[nt];
        outB[(size_t)row * HID + nt * 16 + cl] = f2bf(o);
      }
    }
  } else {
#pragma unroll
    for (int reg = 0; reg < 4; ++reg) {
      int row = rbase + reg;
#pragma unroll
      for (int nt = 0; nt < NT; ++nt) {
        int col = nt * 16 + cl;
        float vv = acc[nt][reg] + bs[nt];
        if constexpr (MODE == 0) outF[(size_t)row * (NT * 16) + col] = vv;
        else outB[(size_t)row * (NT * 16) + col] = f2bf(vv);
      }
    }
  }
}

// ---------------- edge aggregation (unroll-4) ----------------
__global__ __launch_bounds__(256) void aggregate_kernel(
    const unsigned int* __restrict__ pq32, const float* __restrict__ bm1,
    const int* __restrict__ offsets, const int* __restrict__ csr,
    unsigned int* __restrict__ rb32) {
  int node = blockIdx.x * 4 + (threadIdx.x >> 6);
  if (node >= N_NODES) return;
  int lane = threadIdx.x & 63;
  unsigned int qu = pq32[(size_t)node * 128 + 64 + lane];
  float2 bv = *(const float2*)&bm1[2 * lane];
  float q0 = bflo(qu) + bv.x;
  float q1 = bfhi(qu) + bv.y;
  float a0 = 0.f, a1 = 0.f;
  int i0 = offsets[node], i1 = offsets[node + 1];
  int idx = i0;
  for (; idx + 3 < i1; idx += 4) {
    int s0 = csr[idx], s1 = csr[idx + 1], s2 = csr[idx + 2], s3 = csr[idx + 3];
    unsigned int u0 = pq32[(size_t)s0 * 128 + lane];
    unsigned int u1 = pq32[(size_t)s1 * 128 + lane];
    unsigned int u2 = pq32[(size_t)s2 * 128 + lane];
    unsigned int u3 = pq32[(size_t)s3 * 128 + lane];
    a0 += fmaxf(bflo(u0) + q0, 0.f) + fmaxf(bflo(u1) + q0, 0.f) +
          fmaxf(bflo(u2) + q0, 0.f) + fmaxf(bflo(u3) + q0, 0.f);
    a1 += fmaxf(bfhi(u0) + q1, 0.f) + fmaxf(bfhi(u1) + q1, 0.f) +
          fmaxf(bfhi(u2) + q1, 0.f) + fmaxf(bfhi(u3) + q1, 0.f);
  }
  for (; idx < i1; ++idx) {
    unsigned int u0 = pq32[(size_t)csr[idx] * 128 + lane];
    a0 += fmaxf(bflo(u0) + q0, 0.f);
    a1 += fmaxf(bfhi(u0) + q1, 0.f);
  }
  rb32[(size_t)node * 64 + lane] = pack2(a0, a1);
}

extern "C" void kernel_launch(void* const* d_in, const int* in_sizes, int n_in,
                              void* d_out, int out_size, void* d_ws, size_t ws_size,
                              hipStream_t stream) {
  const float* x     = (const float*)d_in[0];
  const int*   ei    = (const int*)d_in[1];
  const float* W_enc = (const float*)d_in[2];
  const float* b_enc = (const float*)d_in[3];
  const float* Wm1   = (const float*)d_in[4];  // [2][128][256]
  const float* bm1   = (const float*)d_in[5];
  const float* Wm2   = (const float*)d_in[6];  // [2][128][128]
  const float* bm2   = (const float*)d_in[7];
  const float* Wu    = (const float*)d_in[8];  // [2][128][256]
  const float* bu    = (const float*)d_in[9];
  const float* gamma = (const float*)d_in[10];
  const float* beta  = (const float*)d_in[11];
  const float* W_out = (const float*)d_in[12];
  const float* b_out = (const float*)d_in[13];
  float* out = (float*)d_out;

  char* ws = (char*)d_ws;
  const size_t NBH = (size_t)N_NODES * HID * 2;  // 12.8 MB bf16 node array

  unsigned short* hb = (unsigned short*)(ws);                  // [N][128] bf16
  unsigned short* pq = (unsigned short*)(ws + NBH);            // [N][256] bf16
  unsigned short* rb = (unsigned short*)(ws + 3 * NBH);        // [N][128] bf16
  char* wp = ws + 4 * NBH;
  unsigned short* Wenc_b = (unsigned short*)wp;                // 16384
  unsigned short* Wout_b = Wenc_b + 16384;                     // 16384
  unsigned short* Wpq_b  = Wout_b + 16384;                     // 2*32768
  unsigned short* Wcat_b = Wpq_b + 65536;                      // 2*32768
  float*          bfold  = (float*)(Wcat_b + 65536);           // 2*128
  int* counts  = (int*)(bfold + 256);
  int* offsets = counts + N_NODES;
  int* cursor  = offsets + N_NODES + 1;
  int* csr     = cursor + N_NODES;

  // weight prep
  convert_f32_bf16<<<32, 256, 0, stream>>>(W_enc, (unsigned int*)Wenc_b, 8192);
  convert_f32_bf16<<<32, 256, 0, stream>>>(W_out, (unsigned int*)Wout_b, 8192);
  repack_wpq<<<128, 256, 0, stream>>>(Wm1, (unsigned int*)Wpq_b);
  fold_kernel<<<256, 256, 0, stream>>>(Wu, Wm2, Wcat_b);
  bfold_kernel<<<1, 256, 0, stream>>>(Wu, bm2, bfold);

  // CSR build
  hipMemsetAsync(counts, 0, N_NODES * sizeof(int), stream);
  hist_kernel<<<(N_EDGES + 255) / 256, 256, 0, stream>>>(ei, counts);
  scan_kernel<<<1, 1024, 0, stream>>>(counts, offsets, cursor);
  scatter_kernel<<<(N_EDGES + 255) / 256, 256, 0, stream>>>(ei, cursor, csr);

  const int GB = 782;  // ceil(3125 rowtiles / 4)

  // h = x @ W_enc.T + b_enc  (f32 A, bf16 out)
  mfma_gemm<8, 4, true, false, 1><<<GB, 256, 0, stream>>>(
      x, nullptr, Wenc_b, b_enc, nullptr, nullptr, nullptr, nullptr, nullptr, nullptr, hb);

  for (int l = 0; l < 2; ++l) {
    const unsigned short* Wpql = Wpq_b + l * 32768;
    const unsigned short* Wcatl = Wcat_b + l * 32768;
    const float* bm1l = bm1 + l * HID;
    const float* bul  = bu + l * HID;
    const float* bfl  = bfold + l * HID;
    const float* gl   = gamma + l * HID;
    const float* bl   = beta + l * HID;

    // pq = h @ [Wm1a|Wm1b].T  -> [N][256] bf16
    mfma_gemm<16, 4, false, false, 1><<<GB, 256, 0, stream>>>(
        hb, nullptr, Wpql, nullptr, nullptr, nullptr, nullptr, nullptr, nullptr, nullptr, pq);
    // r = segsum(relu(p[src]+q[dst]+bm1))
    aggregate_kernel<<<12500, 256, 0, stream>>>((const unsigned int*)pq, bm1l, offsets, csr,
                                                (unsigned int*)rb);
    // h = LN(h + h@Wua.T + r@Wfold.T + deg*bfold + bu)*gamma+beta   (in-place on hb)
    mfma_gemm<8, 8, false, true, 2><<<GB, 256, 0, stream>>>(
        hb, rb, Wcatl, bul, counts, bfl, gl, bl, hb, nullptr, hb);
  }

  // out = h @ W_out.T + b_out  (f32)
  mfma_gemm<8, 4, false, false, 0><<<GB, 256, 0, stream>>>(
      hb, nullptr, Wout_b, b_out, nullptr, nullptr, nullptr, nullptr, nullptr, out, nullptr);
}

// Round 6
// 259.901 us; speedup vs baseline: 4.3965x; 1.2816x over previous
//
#include <hip/hip_runtime.h>

#define N_NODES 50000
#define N_EDGES 800000
#define HID 128
#define EPS 1e-5f
#define NPART 8
#define PSIZE 6250  // N_NODES / NPART

typedef __attribute__((ext_vector_type(8))) short s16x8;   // 8 bf16 (4 VGPRs)
typedef __attribute__((ext_vector_type(4))) float f32x4;   // MFMA acc
typedef __attribute__((ext_vector_type(4))) int i32x4;

__device__ __forceinline__ unsigned short f2bf(float f) {  // RNE f32->bf16
  unsigned int u = __float_as_uint(f);
  u += 0x7fffu + ((u >> 16) & 1u);
  return (unsigned short)(u >> 16);
}
__device__ __forceinline__ unsigned int pack2(float a, float b) {
  return (unsigned int)f2bf(a) | ((unsigned int)f2bf(b) << 16);
}
__device__ __forceinline__ float bflo(unsigned int u) { return __uint_as_float(u << 16); }
__device__ __forceinline__ float bfhi(unsigned int u) { return __uint_as_float(u & 0xffff0000u); }
__device__ __forceinline__ float bf2f(unsigned short u) { return __uint_as_float((unsigned int)u << 16); }

// ================= CSR build, XCD-partitioned =================
// partition = dst / PSIZE; block handles only edges whose dst is in its partition ->
// counts/cursor/csr lines are written by one XCD (blockIdx&7 ~ round-robin XCD map).
__global__ __launch_bounds__(256) void hist2_kernel(const int* __restrict__ ei,
                                                    int* __restrict__ counts) {
  const int part = blockIdx.x & 7;
  const int slice = blockIdx.x >> 3;  // 128 slices of 6250 edges
  const int e0 = slice * 6250;
  for (int e = e0 + threadIdx.x; e < e0 + 6250; e += 256) {
    int c = ei[N_EDGES + e];
    if (c / PSIZE == part) atomicAdd(&counts[c], 1);
  }
}

__global__ __launch_bounds__(256) void scatter2_kernel(const int* __restrict__ ei,
                                                       int* __restrict__ cursor,
                                                       int* __restrict__ csr) {
  const int part = blockIdx.x & 7;
  const int slice = blockIdx.x >> 3;
  const int e0 = slice * 6250;
  for (int e = e0 + threadIdx.x; e < e0 + 6250; e += 256) {
    int c = ei[N_EDGES + e];
    if (c / PSIZE == part) {
      int pos = atomicAdd(&cursor[c], 1);
      csr[pos] = ei[e];
    }
  }
}

// scan pass A: per-256-node block sums
__global__ __launch_bounds__(256) void scan_a_kernel(const int* __restrict__ counts,
                                                     int* __restrict__ bsum) {
  __shared__ int ws[4];
  int i = blockIdx.x * 256 + threadIdx.x;
  int v = (i < N_NODES) ? counts[i] : 0;
  int s = v;
#pragma unroll
  for (int m = 1; m < 64; m <<= 1) s += __shfl_xor(s, m);
  if ((threadIdx.x & 63) == 0) ws[threadIdx.x >> 6] = s;
  __syncthreads();
  if (threadIdx.x == 0) bsum[blockIdx.x] = ws[0] + ws[1] + ws[2] + ws[3];
}

// scan pass B: block prefix (redundant per-block) + local exclusive scan -> offsets,cursor
__global__ __launch_bounds__(256) void scan_b_kernel(const int* __restrict__ counts,
                                                     const int* __restrict__ bsum,
                                                     int* __restrict__ offsets,
                                                     int* __restrict__ cursor) {
  __shared__ int pw[4];
  __shared__ int wtot[4];
  const int b = blockIdx.x, t = threadIdx.x;
  const int lane = t & 63, w = t >> 6;
  // prefix = sum of bsum[0..b)
  int pv = (t < b) ? bsum[t] : 0;  // b <= 195 < 256
  int ps = pv;
#pragma unroll
  for (int m = 1; m < 64; m <<= 1) ps += __shfl_xor(ps, m);
  if (lane == 0) pw[w] = ps;
  // local scan
  int i = b * 256 + t;
  int v = (i < N_NODES) ? counts[i] : 0;
  int s = v;
#pragma unroll
  for (int off = 1; off < 64; off <<= 1) {
    int tt = __shfl_up(s, off);
    if (lane >= off) s += tt;
  }
  if (lane == 63) wtot[w] = s;
  __syncthreads();
  int prefix = pw[0] + pw[1] + pw[2] + pw[3];
  int woff = 0;
#pragma unroll
  for (int j = 0; j < 4; ++j) { int tv = wtot[j]; if (j < w) woff += tv; }
  int excl = prefix + woff + (s - v);
  if (i < N_NODES) { offsets[i] = excl; cursor[i] = excl; }
  if (b == 195 && t == 255)
    offsets[N_NODES] = prefix + wtot[0] + wtot[1] + wtot[2] + wtot[3];
}

// ================= merged weight prep =================
__global__ __launch_bounds__(256) void prep_kernel(
    const float* __restrict__ W_enc, const float* __restrict__ W_out,
    const float* __restrict__ Wm1, const float* __restrict__ Wu,
    const float* __restrict__ Wm2, const float* __restrict__ bm2,
    unsigned int* __restrict__ Wenc_b, unsigned int* __restrict__ Wout_b,
    unsigned int* __restrict__ Wpq_b, unsigned short* __restrict__ Wcat_b,
    float* __restrict__ bfold) {
  const int b = blockIdx.x, t = threadIdx.x;
  if (b < 32) {            // W_enc: 8192 uints
    int i = b * 256 + t;
    Wenc_b[i] = pack2(W_enc[2 * i], W_enc[2 * i + 1]);
  } else if (b < 64) {     // W_out
    int i = (b - 32) * 256 + t;
    Wout_b[i] = pack2(W_out[2 * i], W_out[2 * i + 1]);
  } else if (b < 192) {    // repack Wm1 -> Wpq [l][256 rows][128 k]
    int i = (b - 64) * 256 + t;  // 32768
    int k2 = i & 63;
    int c = (i >> 6) & 255;
    int l = i >> 14;
    const float* srow = Wm1 + ((size_t)l * 128 + (c & 127)) * 256 + ((c >> 7) << 7);
    Wpq_b[i] = pack2(srow[2 * k2], srow[2 * k2 + 1]);
  } else if (b < 448) {    // Wcat: [l][128 rows][256 k], hi-k = Wu_b @ Wm2 fold
    int i = (b - 192) * 256 + t;  // 65536
    int k = i & 255, c = (i >> 8) & 127, l = i >> 15;
    const float* wrow = Wu + ((size_t)l * 128 + c) * 256;
    float v;
    if (k < 128) {
      v = wrow[k];
    } else {
      const float* wb = wrow + 128;
      const float* m2 = Wm2 + (size_t)l * 128 * 128 + (k - 128);
      float s = 0.f;
      for (int j = 0; j < 128; ++j) s += wb[j] * m2[(size_t)j * 128];
      v = s;
    }
    Wcat_b[i] = f2bf(v);
  } else {                 // bfold[l][c] = Wu_b[l][c][:] . bm2[l]
    int l = t >> 7, c = t & 127;
    const float* wb = Wu + ((size_t)l * 128 + c) * 256 + 128;
    const float* bv = bm2 + l * 128;
    float s = 0.f;
    for (int j = 0; j < 128; ++j) s += wb[j] * bv[j];
    bfold[t] = s;
  }
}

// ================= persistent-B MFMA GEMM =================
// B staged to LDS once (fragment-linear), ds_read to REGISTERS once per wave,
// then grid-stride over 16-row tiles: inner loop = A-loads + MFMA only.
// MODE 0: f32 out+bias. MODE 1: bf16 out+bias. MODE 2: fused +residual+LN -> bf16.
// blockIdx.y selects a 128-col half (pq): W row-offset y*128, store col offset y*128.
// In-place (MODE2 on hb): wave's loads (A + hres) precede its stores; tiles disjoint.
template <int KS, bool AF32, bool DUAL, int MODE>
__global__ __launch_bounds__(256, DUAL ? 1 : 2) void gemm3(
    const void* __restrict__ A0v, const unsigned short* __restrict__ A1,
    const unsigned short* __restrict__ W, const float* __restrict__ bias,
    const int* __restrict__ deg, const float* __restrict__ bias2,
    const float* __restrict__ gamma, const float* __restrict__ beta,
    const unsigned short* __restrict__ hres, float* __restrict__ outF,
    unsigned short* __restrict__ outB, int outw) {
  constexpr int KW = KS * 32;
  constexpr int NFRAG = KS * 8;
  __shared__ short Bs[NFRAG * 512];
  const int lane = threadIdx.x & 63;
  const int w = threadIdx.x >> 6;
  const int cl = lane & 15;
  const int kb = (lane >> 4) * 8;
  const int co = blockIdx.y * 128;
  W += (size_t)blockIdx.y * 128 * KW;

  for (int f = w; f < NFRAG; f += 4) {
    int nt = f & 7, ks = f >> 3;
    s16x8 bv = *(const s16x8*)(W + (size_t)(nt * 16 + cl) * KW + ks * 32 + kb);
    *(s16x8*)(Bs + f * 512 + lane * 8) = bv;
  }
  __syncthreads();

  s16x8 breg[KS][8];
#pragma unroll
  for (int ks = 0; ks < KS; ++ks)
#pragma unroll
    for (int nt = 0; nt < 8; ++nt)
      breg[ks][nt] = *(const s16x8*)(Bs + (ks * 8 + nt) * 512 + lane * 8);

  float bs[8], b2[8], gs[8], bes[8];
#pragma unroll
  for (int nt = 0; nt < 8; ++nt) {
    int col = nt * 16 + cl;
    bs[nt] = bias ? bias[col] : 0.f;
    if constexpr (MODE == 2) {
      b2[nt] = bias2[col];
      gs[nt] = gamma[col];
      bes[nt] = beta[col];
    }
  }

  const int step = gridDim.x * 4;
  for (int rt = blockIdx.x * 4 + w; rt < 3125; rt += step) {  // 3125*16 == 50000
    const int arow = rt * 16 + cl;
    f32x4 acc[8];
#pragma unroll
    for (int i = 0; i < 8; ++i) acc[i] = (f32x4){0.f, 0.f, 0.f, 0.f};
#pragma unroll
    for (int ks = 0; ks < KS; ++ks) {
      s16x8 a;
      if constexpr (AF32) {
        const float* ap = (const float*)A0v + (size_t)arow * HID + ks * 32 + kb;
        float4 lo = *(const float4*)ap;
        float4 hi = *(const float4*)(ap + 4);
        i32x4 ai = {(int)pack2(lo.x, lo.y), (int)pack2(lo.z, lo.w),
                    (int)pack2(hi.x, hi.y), (int)pack2(hi.z, hi.w)};
        a = __builtin_bit_cast(s16x8, ai);
      } else if constexpr (DUAL) {
        const unsigned short* base = (ks < KS / 2) ? (const unsigned short*)A0v : A1;
        int kss = (ks < KS / 2) ? ks : ks - KS / 2;
        a = *(const s16x8*)(base + (size_t)arow * HID + kss * 32 + kb);
      } else {
        a = *(const s16x8*)((const unsigned short*)A0v + (size_t)arow * HID + ks * 32 + kb);
      }
#pragma unroll
      for (int nt = 0; nt < 8; ++nt)
        acc[nt] = __builtin_amdgcn_mfma_f32_16x16x32_bf16(a, breg[ks][nt], acc[nt], 0, 0, 0);
    }

    const int rbase = rt * 16 + (lane >> 4) * 4;
    if constexpr (MODE == 2) {
#pragma unroll
      for (int reg = 0; reg < 4; ++reg) {
        int row = rbase + reg;
        float dv = (float)deg[row];
        float v[8];
        float s = 0.f, s2 = 0.f;
#pragma unroll
        for (int nt = 0; nt < 8; ++nt) {
          float hv = bf2f(hres[(size_t)row * HID + nt * 16 + cl]);
          v[nt] = acc[nt][reg] + bs[nt] + dv * b2[nt] + hv;
          s += v[nt];
          s2 += v[nt] * v[nt];
        }
#pragma unroll
        for (int m = 1; m < 16; m <<= 1) {
          s += __shfl_xor(s, m);
          s2 += __shfl_xor(s2, m);
        }
        float mu = s * (1.f / 128.f);
        float var = s2 * (1.f / 128.f) - mu * mu;
        float inv = rsqrtf(var + EPS);
#pragma unroll
        for (int nt = 0; nt < 8; ++nt) {
          float o = (v[nt] - mu) * inv * gs[nt] + bes[nt];
          outB[(size_t)row * HID + nt * 16 + cl] = f2bf(o);
        }
      }
    } else {
#pragma unroll
      for (int reg = 0; reg < 4; ++reg) {
        int row = rbase + reg;
#pragma unroll
        for (int nt = 0; nt < 8; ++nt) {
          float vv = acc[nt][reg] + bs[nt];
          if constexpr (MODE == 0) outF[(size_t)row * outw + co + nt * 16 + cl] = vv;
          else outB[(size_t)row * outw + co + nt * 16 + cl] = f2bf(vv);
        }
      }
    }
  }
}

// ================= edge aggregation: 32 lanes/node, uint2 loads, unroll 4 =================
__global__ __launch_bounds__(256) void aggregate_kernel(
    const unsigned int* __restrict__ pq32, const float* __restrict__ bm1,
    const int* __restrict__ offsets, const int* __restrict__ csr,
    unsigned int* __restrict__ rb32) {
  const int node = blockIdx.x * 8 + (threadIdx.x >> 5);
  const int l = threadIdx.x & 31;
  uint2 qv = *(const uint2*)(pq32 + (size_t)node * 128 + 64 + 2 * l);
  float4 bv = *(const float4*)(bm1 + 4 * l);
  float q0 = bflo(qv.x) + bv.x, q1 = bfhi(qv.x) + bv.y;
  float q2 = bflo(qv.y) + bv.z, q3 = bfhi(qv.y) + bv.w;
  float a0 = 0.f, a1 = 0.f, a2 = 0.f, a3 = 0.f;
  const int i1 = offsets[node + 1];
  int idx = offsets[node];
  for (; idx + 3 < i1; idx += 4) {
    int s0 = csr[idx], s1 = csr[idx + 1], s2 = csr[idx + 2], s3 = csr[idx + 3];
    uint2 u0 = *(const uint2*)(pq32 + (size_t)s0 * 128 + 2 * l);
    uint2 u1 = *(const uint2*)(pq32 + (size_t)s1 * 128 + 2 * l);
    uint2 u2 = *(const uint2*)(pq32 + (size_t)s2 * 128 + 2 * l);
    uint2 u3 = *(const uint2*)(pq32 + (size_t)s3 * 128 + 2 * l);
    a0 += fmaxf(bflo(u0.x) + q0, 0.f) + fmaxf(bflo(u1.x) + q0, 0.f) +
          fmaxf(bflo(u2.x) + q0, 0.f) + fmaxf(bflo(u3.x) + q0, 0.f);
    a1 += fmaxf(bfhi(u0.x) + q1, 0.f) + fmaxf(bfhi(u1.x) + q1, 0.f) +
          fmaxf(bfhi(u2.x) + q1, 0.f) + fmaxf(bfhi(u3.x) + q1, 0.f);
    a2 += fmaxf(bflo(u0.y) + q2, 0.f) + fmaxf(bflo(u1.y) + q2, 0.f) +
          fmaxf(bflo(u2.y) + q2, 0.f) + fmaxf(bflo(u3.y) + q2, 0.f);
    a3 += fmaxf(bfhi(u0.y) + q3, 0.f) + fmaxf(bfhi(u1.y) + q3, 0.f) +
          fmaxf(bfhi(u2.y) + q3, 0.f) + fmaxf(bfhi(u3.y) + q3, 0.f);
  }
  for (; idx < i1; ++idx) {
    uint2 u0 = *(const uint2*)(pq32 + (size_t)csr[idx] * 128 + 2 * l);
    a0 += fmaxf(bflo(u0.x) + q0, 0.f);
    a1 += fmaxf(bfhi(u0.x) + q1, 0.f);
    a2 += fmaxf(bflo(u0.y) + q2, 0.f);
    a3 += fmaxf(bfhi(u0.y) + q3, 0.f);
  }
  uint2 r;
  r.x = pack2(a0, a1);
  r.y = pack2(a2, a3);
  *(uint2*)(rb32 + (size_t)node * 64 + 2 * l) = r;
}

extern "C" void kernel_launch(void* const* d_in, const int* in_sizes, int n_in,
                              void* d_out, int out_size, void* d_ws, size_t ws_size,
                              hipStream_t stream) {
  const float* x     = (const float*)d_in[0];
  const int*   ei    = (const int*)d_in[1];
  const float* W_enc = (const float*)d_in[2];
  const float* b_enc = (const float*)d_in[3];
  const float* Wm1   = (const float*)d_in[4];
  const float* bm1   = (const float*)d_in[5];
  const float* Wm2   = (const float*)d_in[6];
  const float* bm2   = (const float*)d_in[7];
  const float* Wu    = (const float*)d_in[8];
  const float* bu    = (const float*)d_in[9];
  const float* gamma = (const float*)d_in[10];
  const float* beta  = (const float*)d_in[11];
  const float* W_out = (const float*)d_in[12];
  const float* b_out = (const float*)d_in[13];
  float* out = (float*)d_out;

  char* ws = (char*)d_ws;
  const size_t NBH = (size_t)N_NODES * HID * 2;  // 12.8 MB

  unsigned short* hb = (unsigned short*)(ws);            // [N][128] bf16
  unsigned short* pq = (unsigned short*)(ws + NBH);      // [N][256] bf16
  unsigned short* rb = (unsigned short*)(ws + 3 * NBH);  // [N][128] bf16
  char* wp = ws + 4 * NBH;
  unsigned short* Wenc_b = (unsigned short*)wp;          // 16384
  unsigned short* Wout_b = Wenc_b + 16384;               // 16384
  unsigned short* Wpq_b  = Wout_b + 16384;               // 2*32768
  unsigned short* Wcat_b = Wpq_b + 65536;                // 2*32768
  float*          bfold  = (float*)(Wcat_b + 65536);     // 256
  int* counts  = (int*)(bfold + 256);
  int* offsets = counts + N_NODES;
  int* cursor  = offsets + N_NODES + 1;
  int* csr     = cursor + N_NODES;
  int* bsum    = csr + N_EDGES;                          // 196

  // weight prep (1 launch) + CSR build (partitioned)
  prep_kernel<<<449, 256, 0, stream>>>(W_enc, W_out, Wm1, Wu, Wm2, bm2,
                                       (unsigned int*)Wenc_b, (unsigned int*)Wout_b,
                                       (unsigned int*)Wpq_b, Wcat_b, bfold);
  hipMemsetAsync(counts, 0, N_NODES * sizeof(int), stream);
  hist2_kernel<<<1024, 256, 0, stream>>>(ei, counts);
  scan_a_kernel<<<196, 256, 0, stream>>>(counts, bsum);
  scan_b_kernel<<<196, 256, 0, stream>>>(counts, bsum, offsets, cursor);
  scatter2_kernel<<<1024, 256, 0, stream>>>(ei, cursor, csr);

  // h = x @ W_enc.T + b_enc  -> bf16 hb
  gemm3<4, true, false, 1><<<512, 256, 0, stream>>>(
      x, nullptr, Wenc_b, b_enc, nullptr, nullptr, nullptr, nullptr, nullptr,
      nullptr, hb, HID);

  for (int l = 0; l < 2; ++l) {
    const unsigned short* Wpql  = Wpq_b + l * 32768;
    const unsigned short* Wcatl = Wcat_b + l * 32768;
    const float* bm1l = bm1 + l * HID;
    const float* bul  = bu + l * HID;
    const float* bfl  = bfold + l * HID;
    const float* gl   = gamma + l * HID;
    const float* bl   = beta + l * HID;

    // pq = h @ [Wm1a|Wm1b].T -> [N][256] bf16 (blockIdx.y halves)
    gemm3<4, false, false, 1><<<dim3(512, 2), 256, 0, stream>>>(
        hb, nullptr, Wpql, nullptr, nullptr, nullptr, nullptr, nullptr, nullptr,
        nullptr, pq, 256);
    // r = segsum(relu(p[src]+q[dst]+bm1))
    aggregate_kernel<<<6250, 256, 0, stream>>>((const unsigned int*)pq, bm1l, offsets,
                                               csr, (unsigned int*)rb);
    // h = LN(h + h@Wua.T + r@Wfold.T + deg*bfold + bu)*gamma+beta (in-place)
    gemm3<8, false, true, 2><<<256, 256, 0, stream>>>(
        hb, rb, Wcatl, bul, counts, bfl, gl, bl, hb, nullptr, hb, HID);
  }

  // out = h @ W_out.T + b_out (f32)
  gemm3<4, false, false, 0><<<512, 256, 0, stream>>>(
      hb, nullptr, Wout_b, b_out, nullptr, nullptr, nullptr, nullptr, nullptr,
      out, nullptr, HID);
}